// Round 3
// baseline (47.755 us; speedup 1.0000x reference)
//
#include <hip/hip_runtime.h>
#include <hip/hip_bf16.h>

#define NSEG 196
#define NSEGP 208   // padded so the 4 SoA arrays stagger bank offsets
#define C_OUT 56
#define B_IMG 32
#define HW (224 * 224)
#define NCHUNK 16
#define NVEC (HW / 4)          // 12544 float4 per channel plane
#define VPC (NVEC / NCHUNK)    // 784 vec4 per chunk (exact)

// partial layout: [B][NCHUNK][4*NSEG] floats, component-major:
//   [0..195]=sum_c0, [196..391]=sum_c1, [392..587]=sum_c2, [588..783]=count
// Every slot written unconditionally -> no zero-init of ws needed.

__global__ void __launch_bounds__(256) spm_accum_kernel(
    const float* __restrict__ X,      // (B, 3, H, W)
    const int* __restrict__ seg,      // (B, H, W)
    float* __restrict__ partial)      // (B, NCHUNK, 4*NSEG)
{
    // SoA accumulators: bank = seg % 32 -> all 32 banks in play (was 8 with AoS)
    __shared__ float a0[NSEGP];
    __shared__ float a1[NSEGP];
    __shared__ float a2[NSEGP];
    __shared__ float ac[NSEGP];

    const int tid = threadIdx.x;
    for (int i = tid; i < NSEGP; i += 256) {
        a0[i] = 0.0f; a1[i] = 0.0f; a2[i] = 0.0f; ac[i] = 0.0f;
    }
    __syncthreads();

    const int b = blockIdx.x;
    const int chunk = blockIdx.y;
    const float* Xb = X + (size_t)b * 3 * HW;
    const int* segb = seg + (size_t)b * HW;

    const float4* x0p = (const float4*)(Xb);
    const float4* x1p = (const float4*)(Xb + HW);
    const float4* x2p = (const float4*)(Xb + 2 * HW);
    const int4* sp = (const int4*)(segb);

    const int vend = (chunk + 1) * VPC;
    for (int v = chunk * VPC + tid; v < vend; v += 256) {
        int4 s4 = sp[v];
        float4 x0 = x0p[v];
        float4 x1 = x1p[v];
        float4 x2 = x2p[v];

        atomicAdd(&a0[s4.x], x0.x);
        atomicAdd(&a1[s4.x], x1.x);
        atomicAdd(&a2[s4.x], x2.x);
        atomicAdd(&ac[s4.x], 1.0f);

        atomicAdd(&a0[s4.y], x0.y);
        atomicAdd(&a1[s4.y], x1.y);
        atomicAdd(&a2[s4.y], x2.y);
        atomicAdd(&ac[s4.y], 1.0f);

        atomicAdd(&a0[s4.z], x0.z);
        atomicAdd(&a1[s4.z], x1.z);
        atomicAdd(&a2[s4.z], x2.z);
        atomicAdd(&ac[s4.z], 1.0f);

        atomicAdd(&a0[s4.w], x0.w);
        atomicAdd(&a1[s4.w], x1.w);
        atomicAdd(&a2[s4.w], x2.w);
        atomicAdd(&ac[s4.w], 1.0f);
    }
    __syncthreads();

    float* dst = partial + ((size_t)b * NCHUNK + chunk) * (4 * NSEG);
    for (int i = tid; i < 4 * NSEG; i += 256) {
        int comp = i / NSEG;
        int sg = i - comp * NSEG;
        float v = (comp == 0) ? a0[sg] : (comp == 1) ? a1[sg]
                : (comp == 2) ? a2[sg] : ac[sg];
        dst[i] = v;
    }
}

__global__ void __launch_bounds__(256) spm_finalize_kernel(
    const float* __restrict__ partial, // (B, NCHUNK, 4*NSEG)
    const float* __restrict__ Wm,      // (C_OUT, 3)
    const float* __restrict__ bias,    // (C_OUT)
    float* __restrict__ out)           // (B, NSEG, C_OUT)
{
    __shared__ float acc[4 * NSEG];
    __shared__ float Ws[C_OUT * 3];
    __shared__ float bs[C_OUT];

    const int tid = threadIdx.x;
    const int b = blockIdx.x;

    if (tid < C_OUT * 3) Ws[tid] = Wm[tid];
    if (tid < C_OUT) bs[tid] = bias[tid];

    const float* src = partial + (size_t)b * NCHUNK * (4 * NSEG);
    for (int i = tid; i < 4 * NSEG; i += 256) {
        float s = 0.0f;
        #pragma unroll
        for (int c = 0; c < NCHUNK; ++c) s += src[c * (4 * NSEG) + i];
        acc[i] = s;
    }
    __syncthreads();

    float* outb = out + (size_t)b * NSEG * C_OUT;
    for (int idx = tid; idx < NSEG * C_OUT; idx += 256) {
        int sg = idx / C_OUT;
        int o = idx - sg * C_OUT;
        float s0 = acc[0 * NSEG + sg];
        float s1 = acc[1 * NSEG + sg];
        float s2 = acc[2 * NSEG + sg];
        float cnt = acc[3 * NSEG + sg];
        float inv = 1.0f / fmaxf(cnt, 1.0f);
        outb[idx] = (Ws[o * 3 + 0] * s0 + Ws[o * 3 + 1] * s1 + Ws[o * 3 + 2] * s2) * inv
                    + bs[o];
    }
}

extern "C" void kernel_launch(void* const* d_in, const int* in_sizes, int n_in,
                              void* d_out, int out_size, void* d_ws, size_t ws_size,
                              hipStream_t stream) {
    const float* X = (const float*)d_in[0];
    const int* seg = (const int*)d_in[1];
    const float* Wm = (const float*)d_in[2];
    const float* bias = (const float*)d_in[3];
    float* out = (float*)d_out;
    float* ws = (float*)d_ws;

    dim3 grid1(B_IMG, NCHUNK);
    spm_accum_kernel<<<grid1, 256, 0, stream>>>(X, seg, ws);
    spm_finalize_kernel<<<B_IMG, 256, 0, stream>>>(ws, Wm, bias, out);
}